// Round 2
// baseline (408.421 us; speedup 1.0000x reference)
//
#include <hip/hip_runtime.h>
#include <hip/hip_bf16.h>
#include <stdint.h>

typedef unsigned short u16;
typedef unsigned int u32;

using bf16x8 = __attribute__((ext_vector_type(8))) __bf16;  // 4 VGPRs: MFMA A/B operand
using f32x4  = __attribute__((ext_vector_type(4))) float;   // MFMA C/D operand

#define AS1 __attribute__((address_space(1)))
#define AS3 __attribute__((address_space(3)))

// fp32 -> bf16 round-to-nearest-even
__device__ __forceinline__ u16 f2bf(float x) {
  u32 u = __float_as_uint(x);
  u = (u + 0x7FFFu + ((u >> 16) & 1u)) >> 16;
  return (u16)u;
}
__device__ __forceinline__ float bf2f(u32 bits) { return __uint_as_float(bits << 16); }

// async global->LDS, 16B per lane. LDS dest = wave-uniform base + lane*16.
__device__ __forceinline__ void gload16(const void* g, void* l) {
  __builtin_amdgcn_global_load_lds((AS1 void*)(const_cast<void*>(g)),
                                   (AS3 void*)l, 16, 0, 0);
}

// load 16 contiguous bf16 (32B, aligned) into 16 floats
__device__ __forceinline__ void load16bf(const u16* p, float* f) {
  uint4 a = *(const uint4*)(p);
  uint4 b = *(const uint4*)(p + 8);
  u32 v[8] = {a.x, a.y, a.z, a.w, b.x, b.y, b.z, b.w};
#pragma unroll
  for (int i = 0; i < 8; ++i) {
    f[2 * i]     = __uint_as_float(v[i] << 16);
    f[2 * i + 1] = __uint_as_float(v[i] & 0xFFFF0000u);
  }
}

// ---------------------------------------------------------------------------
// Zero-init workspace control structures: T[65536] fp32, rows[4608]=-1,
// meta[96]=0 (counts 8 | cursors 8 | tile_expert 72 | pad).
// ---------------------------------------------------------------------------
__global__ __launch_bounds__(256) void k_zero(float* __restrict__ T,
                                              int* __restrict__ rows,
                                              int* __restrict__ meta) {
  int i = blockIdx.x * 256 + threadIdx.x;
  if (i < 65536) { T[i] = 0.f; return; }
  i -= 65536;
  if (i < 4608) { rows[i] = -1; return; }
  i -= 4608;
  if (i < 96) meta[i] = 0;
}

// ---------------------------------------------------------------------------
// Convert / repack all weights to bf16 (scale 2.0 = LORA_SCALE folded into B1,B2;
// A2 transposed to [e][h][r] for contiguous 32B reads per h).
// ---------------------------------------------------------------------------
__global__ __launch_bounds__(256) void k_cvt(
    const float* __restrict__ hs, const float* __restrict__ W1,
    const float* __restrict__ W2, const float* __restrict__ A1,
    const float* __restrict__ B1, const float* __restrict__ B2,
    const float* __restrict__ A2,
    u16* __restrict__ Xbf, u16* __restrict__ W1bf, u16* __restrict__ W2bf,
    u16* __restrict__ A1bf, u16* __restrict__ B1s, u16* __restrict__ B2s,
    u16* __restrict__ A2t) {
  int i = blockIdx.x * 256 + threadIdx.x;
  if (i < 2097152) { Xbf[i] = f2bf(hs[i]); return; }
  i -= 2097152;
  if (i < 4194304) { W1bf[i] = f2bf(W1[i]); return; }
  i -= 4194304;
  if (i < 4194304) { W2bf[i] = f2bf(W2[i]); return; }
  i -= 4194304;
  if (i < 131072) { A1bf[i] = f2bf(A1[i]); return; }
  i -= 131072;
  if (i < 524288) { B1s[i] = f2bf(2.0f * B1[i]); return; }  // [E,H,R] kept
  i -= 524288;
  if (i < 131072) { B2s[i] = f2bf(2.0f * B2[i]); return; }  // [E,D,R] kept
  i -= 131072;
  // A2 [E,R,H] -> A2t [E,H,R]
  int e = i >> 16, rem = i & 65535, r = rem >> 12, h = rem & 4095;
  A2t[(e << 16) + h * 16 + r] = f2bf(A2[i]);
}

// ---------------------------------------------------------------------------
// Router: 1 wave per token; top-2 renormalized softmax = sigmoid(l1-l0).
// Also counts pairs per expert for the sort.
// ---------------------------------------------------------------------------
__global__ __launch_bounds__(256) void k_router(
    const float* __restrict__ x, const float* __restrict__ gate,
    int* __restrict__ sel, float* __restrict__ wgt, int* __restrict__ cnt) {
  const int lane = threadIdx.x & 63;
  const int wv = threadIdx.x >> 6;
  const int t = blockIdx.x * 4 + wv;
  const float* xp = x + (size_t)t * 1024 + lane * 16;
  float4 xv[4];
#pragma unroll
  for (int i = 0; i < 4; ++i) xv[i] = *(const float4*)(xp + i * 4);
  float acc[8];
#pragma unroll
  for (int e = 0; e < 8; ++e) {
    const float* gp = gate + e * 1024 + lane * 16;
    float s = 0.f;
#pragma unroll
    for (int i = 0; i < 4; ++i) {
      float4 g = *(const float4*)(gp + i * 4);
      s += xv[i].x * g.x + xv[i].y * g.y + xv[i].z * g.z + xv[i].w * g.w;
    }
    acc[e] = s;
  }
#pragma unroll
  for (int e = 0; e < 8; ++e)
    for (int off = 32; off > 0; off >>= 1) acc[e] += __shfl_xor(acc[e], off);
  if (lane == 0) {
    int e0 = 0; float l0 = acc[0];
#pragma unroll
    for (int e = 1; e < 8; ++e) if (acc[e] > l0) { l0 = acc[e]; e0 = e; }
    int e1 = (e0 == 0) ? 1 : 0; float l1 = acc[e1];
#pragma unroll
    for (int e = 0; e < 8; ++e)
      if (e != e0 && acc[e] > l1) { l1 = acc[e]; e1 = e; }
    float p = 1.f / (1.f + __expf(l1 - l0));
    sel[2 * t] = e0; sel[2 * t + 1] = e1;
    wgt[2 * t] = p;  wgt[2 * t + 1] = 1.f - p;
    atomicAdd(&cnt[e0], 1);
    atomicAdd(&cnt[e1], 1);
  }
}

// ---------------------------------------------------------------------------
// Serial scan: per-expert segment starts (padded to 64), tile->expert map.
// ---------------------------------------------------------------------------
__global__ void k_scan(const int* __restrict__ counts, int* __restrict__ cursors,
                       int* __restrict__ tile_expert) {
  if (threadIdx.x == 0 && blockIdx.x == 0) {
    int off = 0;
    for (int e = 0; e < 8; ++e) {
      cursors[e] = off;
      int pc = (counts[e] + 63) & ~63;
      for (int tt = off >> 6; tt < ((off + pc) >> 6); ++tt) tile_expert[tt] = e;
      off += pc;
    }
  }
}

__global__ __launch_bounds__(256) void k_scatter(const int* __restrict__ sel,
                                                 int* __restrict__ cursors,
                                                 int* __restrict__ rows) {
  int t = blockIdx.x * 256 + threadIdx.x;
  if (t >= 2048) return;
  int e0 = sel[2 * t], e1 = sel[2 * t + 1];
  rows[atomicAdd(&cursors[e0], 1)] = 2 * t;
  rows[atomicAdd(&cursors[e1], 1)] = 2 * t + 1;
}

// ---------------------------------------------------------------------------
// bf16 GEMM, C[m,n] = sum_k A[m,k]*B[n,k] (+bias[n] on bf16 path).
// 128x128 tile, BK=64, 256 threads, 16x16x32 MFMA, global_load_lds w=16,
// XOR chunk swizzle. blockIdx.z = split-K slice.
// ---------------------------------------------------------------------------
__global__ __launch_bounds__(256, 2) void gemm_bt(
    const u16* __restrict__ A, const u16* __restrict__ B, void* __restrict__ Cv,
    int K, int ldc, int Ksub, size_t Cstride_elems, int outbf,
    const float* __restrict__ bias) {
  __shared__ alignas(16) u16 lsA[128 * 64];
  __shared__ alignas(16) u16 lsB[128 * 64];
  const int tid = threadIdx.x;
  const int lane = tid & 63;
  const int w = tid >> 6;
  const int m0 = blockIdx.x * 128;
  const int n0 = blockIdx.y * 128;
  const int z = blockIdx.z;
  const int wm = w & 1, wn = w >> 1;

  f32x4 acc[4][4] = {};

  const int sr = lane >> 3;
  const int sc = lane & 7;
  const int cg = sc ^ sr;
  const u16* Ag = A + (size_t)(m0 + w * 32 + sr) * K + (size_t)z * Ksub + cg * 8;
  const u16* Bg = B + (size_t)(n0 + w * 32 + sr) * K + (size_t)z * Ksub + cg * 8;
  u16* lA = lsA + w * 2048;
  u16* lB = lsB + w * 2048;

  const int fr = lane & 15;
  const int fq = lane >> 4;

  for (int kt = 0; kt < Ksub; kt += 64) {
#pragma unroll
    for (int j = 0; j < 4; ++j) {
      gload16(Ag + (size_t)j * 8 * K, lA + j * 512);
      gload16(Bg + (size_t)j * 8 * K, lB + j * 512);
    }
    Ag += 64; Bg += 64;
    __syncthreads();
#pragma unroll
    for (int s = 0; s < 2; ++s) {
      const int cl = (s * 4 + fq) ^ (fr & 7);
      bf16x8 av[4], bv[4];
#pragma unroll
      for (int i = 0; i < 4; ++i)
        av[i] = *(const bf16x8*)&lsA[(wm * 64 + i * 16 + fr) * 64 + cl * 8];
#pragma unroll
      for (int j = 0; j < 4; ++j)
        bv[j] = *(const bf16x8*)&lsB[(wn * 64 + j * 16 + fr) * 64 + cl * 8];
#pragma unroll
      for (int i = 0; i < 4; ++i)
#pragma unroll
        for (int j = 0; j < 4; ++j)
          acc[i][j] = __builtin_amdgcn_mfma_f32_16x16x32_bf16(av[i], bv[j], acc[i][j], 0, 0, 0);
    }
    __syncthreads();
  }

  const size_t zoff = (size_t)z * Cstride_elems;
  if (outbf) {
    u16* Co = (u16*)Cv + zoff;
#pragma unroll
    for (int i = 0; i < 4; ++i)
#pragma unroll
      for (int j = 0; j < 4; ++j)
#pragma unroll
        for (int r = 0; r < 4; ++r) {
          int m = m0 + wm * 64 + i * 16 + fq * 4 + r;
          int n = n0 + wn * 64 + j * 16 + fr;
          float bv2 = bias ? bias[n] : 0.f;
          Co[(size_t)m * ldc + n] = f2bf(acc[i][j][r] + bv2);
        }
  } else {
    float* Co = (float*)Cv + zoff;
#pragma unroll
    for (int i = 0; i < 4; ++i)
#pragma unroll
      for (int j = 0; j < 4; ++j)
#pragma unroll
        for (int r = 0; r < 4; ++r) {
          int m = m0 + wm * 64 + i * 16 + fq * 4 + r;
          int n = n0 + wn * 64 + j * 16 + fr;
          Co[(size_t)m * ldc + n] = acc[i][j][r];
        }
  }
}

// ---------------------------------------------------------------------------
// Expert-sorted LoRA1 + silu: block = (sorted tile of 64 rows) x (256 h).
// One h per thread -> B1[e][h][:] lives in 16 registers, reused for 64 rows.
// Per-row token id / weight / LX are wave-uniform -> scalar loads.
// Zw[p,h] = w_p * silu(C1[t,h](+b1 folded) + LX[t,e]·B1s[e][h]).
// ---------------------------------------------------------------------------
__global__ __launch_bounds__(256) void k_lora1(
    const u16* __restrict__ C1, const float* __restrict__ LX,
    const u16* __restrict__ B1s, const int* __restrict__ rows,
    const int* __restrict__ tile_expert, const float* __restrict__ wgt,
    u16* __restrict__ Zw) {
  const int tile = blockIdx.x;
  const int h = blockIdx.y * 256 + threadIdx.x;
  const int e = tile_expert[tile];
  float bw[16];
  load16bf(B1s + (size_t)e * 65536 + (size_t)h * 16, bw);
  const int* rp = rows + tile * 64;
#pragma unroll 2
  for (int i = 0; i < 64; ++i) {
    int p = rp[i];                 // uniform across block
    if (p < 0) continue;
    int t = p >> 1;
    float w = wgt[p];
    const float* lx = LX + t * 128 + e * 16;
    float c = bf2f(C1[(size_t)t * 4096 + h]);
    float d = 0.f;
#pragma unroll
    for (int r = 0; r < 16; ++r) d += lx[r] * bw[r];
    float z = c + d;
    float s = z / (1.f + __expf(-z));
    Zw[(size_t)p * 4096 + h] = f2bf(w * s);
  }
}

// ---------------------------------------------------------------------------
// am[t,h] = Zw[2t,h] + Zw[2t+1,h]  (bf16, vectorized x8)
// ---------------------------------------------------------------------------
__global__ __launch_bounds__(256) void k_am(const u16* __restrict__ Zw,
                                            u16* __restrict__ am) {
  int gid = blockIdx.x * 256 + threadIdx.x;  // 1M threads, 8 elems each
  int t = gid >> 9;
  int hh = (gid & 511) * 8;
  const u16* z0 = Zw + (size_t)(2 * t) * 4096 + hh;
  const u16* z1 = Zw + (size_t)(2 * t + 1) * 4096 + hh;
  uint4 a = *(const uint4*)z0;
  uint4 b = *(const uint4*)z1;
  u32 va[4] = {a.x, a.y, a.z, a.w};
  u32 vb[4] = {b.x, b.y, b.z, b.w};
  u32 out[4];
#pragma unroll
  for (int i = 0; i < 4; ++i) {
    float lo = __uint_as_float(va[i] << 16) + __uint_as_float(vb[i] << 16);
    float hi = __uint_as_float(va[i] & 0xFFFF0000u) + __uint_as_float(vb[i] & 0xFFFF0000u);
    out[i] = (u32)f2bf(lo) | ((u32)f2bf(hi) << 16);
  }
  *(uint4*)(am + (size_t)t * 4096 + hh) = *(uint4*)out;
}

// ---------------------------------------------------------------------------
// T[p,r] = sum_h Zw[p,h] * A2t[e_p][h,r]  (expert-sorted tiles, atomic over
// 8 h-segments). Block = 64 rows x 4 h-subsegments of 128.
// ---------------------------------------------------------------------------
__global__ __launch_bounds__(256) void k_tg(
    const u16* __restrict__ Zw, const u16* __restrict__ A2t,
    const int* __restrict__ rows, const int* __restrict__ tile_expert,
    float* __restrict__ T) {
  __shared__ float sred[64][4][16];
  const int tile = blockIdx.x;
  const int hseg = blockIdx.y;  // 0..7
  const int tid = threadIdx.x;
  const int i = tid >> 2, q = tid & 3;
  const int e = tile_expert[tile];
  int p = rows[tile * 64 + i];
  int p0 = p < 0 ? 0 : p;
  const int hb = hseg * 512 + q * 128;
  float tacc[16] = {};
  const u16* zp = Zw + (size_t)p0 * 4096 + hb;
  const u16* ap = A2t + (size_t)e * 65536 + (size_t)hb * 16;
  for (int jj = 0; jj < 16; ++jj) {
    uint4 zz = *(const uint4*)(zp + jj * 8);
    u32 zv[4] = {zz.x, zz.y, zz.z, zz.w};
#pragma unroll
    for (int j2 = 0; j2 < 8; ++j2) {
      u32 bits = (j2 & 1) ? (zv[j2 >> 1] & 0xFFFF0000u) : (zv[j2 >> 1] << 16);
      float zw = __uint_as_float(bits);
      float a[16];
      load16bf(ap + (jj * 8 + j2) * 16, a);
#pragma unroll
      for (int r = 0; r < 16; ++r) tacc[r] += zw * a[r];
    }
  }
#pragma unroll
  for (int r = 0; r < 16; ++r) sred[i][q][r] = tacc[r];
  __syncthreads();
  {
    int row = tid >> 2, rc = tid & 3;
    int pr = rows[tile * 64 + row];
    if (pr >= 0) {
#pragma unroll
      for (int rr = 0; rr < 4; ++rr) {
        int r = rc * 4 + rr;
        float s = sred[row][0][r] + sred[row][1][r] + sred[row][2][r] + sred[row][3][r];
        atomicAdd(&T[pr * 16 + r], s);
      }
    }
  }
}

// ---------------------------------------------------------------------------
// out = sum_z F2p[z] + b2 + T[2t]·B2s[e0][d] + T[2t+1]·B2s[e1][d]
// ---------------------------------------------------------------------------
__global__ __launch_bounds__(256) void k_final(
    const float* __restrict__ F2p, const float* __restrict__ b2,
    const u16* __restrict__ B2s, const float* __restrict__ T,
    const int* __restrict__ sel, float* __restrict__ out) {
  const int idx = blockIdx.x * 256 + threadIdx.x;
  const int t = idx >> 10, d = idx & 1023;
  const int e0 = sel[2 * t], e1 = sel[2 * t + 1];
  float s = F2p[idx] + F2p[idx + 2097152] + F2p[idx + 4194304] +
            F2p[idx + 6291456] + b2[d];
  float f0[16], f1[16];
  load16bf(B2s + (size_t)e0 * 16384 + d * 16, f0);
  load16bf(B2s + (size_t)e1 * 16384 + d * 16, f1);
  const float* tp0 = T + (2 * t) * 16;
  const float* tp1 = T + (2 * t + 1) * 16;
#pragma unroll
  for (int r = 0; r < 16; ++r) s += tp0[r] * f0[r] + tp1[r] * f1[r];
  out[idx] = s;
}

// ---------------------------------------------------------------------------
extern "C" void kernel_launch(void* const* d_in, const int* in_sizes, int n_in,
                              void* d_out, int out_size, void* d_ws, size_t ws_size,
                              hipStream_t stream) {
  const float* hs   = (const float*)d_in[0];
  const float* gate = (const float*)d_in[1];
  const float* W1   = (const float*)d_in[2];
  const float* b1   = (const float*)d_in[3];
  const float* W2   = (const float*)d_in[4];
  const float* b2   = (const float*)d_in[5];
  const float* A1   = (const float*)d_in[6];
  const float* B1   = (const float*)d_in[7];
  const float* A2   = (const float*)d_in[8];
  const float* B2   = (const float*)d_in[9];

  char* ws = (char*)d_ws;
  size_t off = 0;
  auto alloc = [&](size_t bytes) -> void* {
    void* p = ws + off;
    off += (bytes + 255) & ~(size_t)255;
    return p;
  };
  u16*   Xbf  = (u16*)alloc(2097152ull * 2);        // x bf16 [2048,1024]
  u16*   W1bf = (u16*)alloc(4194304ull * 2);        // [4096,1024]
  u16*   W2bf = (u16*)alloc(4194304ull * 2);        // [1024,4096]
  u16*   A1bf = (u16*)alloc(131072ull * 2);         // [128,1024]
  u16*   B1s  = (u16*)alloc(524288ull * 2);         // 2*B1 [E,4096,16]
  u16*   B2s  = (u16*)alloc(131072ull * 2);         // 2*B2 [E,1024,16]
  u16*   A2t  = (u16*)alloc(524288ull * 2);         // A2^T [E,4096,16]
  u16*   C1   = (u16*)alloc(2048ull * 4096 * 2);    // x@W1^T + b1, bf16
  float* LX   = (float*)alloc(2048ull * 128 * 4);   // x@A1_all^T fp32
  u16*   am   = (u16*)alloc(2048ull * 4096 * 2);    // Zw[2t]+Zw[2t+1]
  u16*   Zw   = (u16*)alloc(4096ull * 4096 * 2);    // w_p*silu per pair (32MB)
  float* F2p  = (float*)Zw;                         // ALIAS: Zw dead before gemm2
  float* T    = (float*)alloc(4096ull * 16 * 4);    // w_p*(a@A2^T) per pair
  int*   sel  = (int*)alloc(2048ull * 2 * 4);
  float* wgt  = (float*)alloc(2048ull * 2 * 4);
  int*   meta = (int*)alloc(96 * 4);                // counts8|cursors8|tilee72
  int*   rows = (int*)alloc(4608 * 4);
  int* counts = meta;
  int* cursors = meta + 8;
  int* tile_expert = meta + 16;

  k_zero<<<275, 256, 0, stream>>>(T, rows, meta);
  k_cvt<<<46080, 256, 0, stream>>>(hs, W1, W2, A1, B1, B2, A2,
                                   Xbf, W1bf, W2bf, A1bf, B1s, B2s, A2t);
  k_router<<<512, 256, 0, stream>>>(hs, gate, sel, wgt, counts);
  k_scan<<<1, 64, 0, stream>>>(counts, cursors, tile_expert);
  k_scatter<<<8, 256, 0, stream>>>(sel, cursors, rows);
  // C1 = X @ W1^T + b1 (bf16), M=2048 N=4096 K=1024
  gemm_bt<<<dim3(16, 32, 1), 256, 0, stream>>>(Xbf, W1bf, (void*)C1, 1024, 4096, 1024, 0, 1, b1);
  // LX = X @ A1_all^T (fp32), N=128
  gemm_bt<<<dim3(16, 1, 1), 256, 0, stream>>>(Xbf, A1bf, (void*)LX, 1024, 128, 1024, 0, 0, nullptr);
  k_lora1<<<dim3(72, 16), 256, 0, stream>>>(C1, LX, B1s, rows, tile_expert, wgt, Zw);
  k_am<<<4096, 256, 0, stream>>>(Zw, am);
  k_tg<<<dim3(72, 8), 256, 0, stream>>>(Zw, A2t, rows, tile_expert, T);
  // F2p[z] = am @ W2^T (split-K=4), M=2048 N=1024 K=4096
  gemm_bt<<<dim3(16, 8, 4), 256, 0, stream>>>(am, W2bf, (void*)F2p, 4096, 1024, 1024, 2097152, 0, nullptr);
  k_final<<<8192, 256, 0, stream>>>(F2p, b2, B2s, T, sel, (float*)d_out);
}

// Round 3
// 333.721 us; speedup vs baseline: 1.2238x; 1.2238x over previous
//
#include <hip/hip_runtime.h>
#include <hip/hip_bf16.h>
#include <stdint.h>

typedef unsigned short u16;
typedef unsigned int u32;

using bf16x8 = __attribute__((ext_vector_type(8))) __bf16;  // 4 VGPRs: MFMA A/B operand
using f32x4  = __attribute__((ext_vector_type(4))) float;   // MFMA C/D operand

#define AS1 __attribute__((address_space(1)))
#define AS3 __attribute__((address_space(3)))

// fp32 -> bf16 round-to-nearest-even
__device__ __forceinline__ u16 f2bf(float x) {
  u32 u = __float_as_uint(x);
  u = (u + 0x7FFFu + ((u >> 16) & 1u)) >> 16;
  return (u16)u;
}
__device__ __forceinline__ float bf2f(u32 bits) { return __uint_as_float(bits << 16); }

// async global->LDS, 16B per lane. LDS dest = wave-uniform base + lane*16.
__device__ __forceinline__ void gload16(const void* g, void* l) {
  __builtin_amdgcn_global_load_lds((AS1 void*)(const_cast<void*>(g)),
                                   (AS3 void*)l, 16, 0, 0);
}

// load 16 contiguous bf16 (32B, aligned) into 16 floats
__device__ __forceinline__ void load16bf(const u16* p, float* f) {
  uint4 a = *(const uint4*)(p);
  uint4 b = *(const uint4*)(p + 8);
  u32 v[8] = {a.x, a.y, a.z, a.w, b.x, b.y, b.z, b.w};
#pragma unroll
  for (int i = 0; i < 8; ++i) {
    f[2 * i]     = __uint_as_float(v[i] << 16);
    f[2 * i + 1] = __uint_as_float(v[i] & 0xFFFF0000u);
  }
}

// ---------------------------------------------------------------------------
// Convert / repack all weights to bf16 (LORA_SCALE=2.0 folded into B1,B2).
// A2 kept in original [E,16,4096] layout (perfect MFMA B-operand for k_tg2).
// Tail segments: zero T, rows=-1, meta=0.
// Sizes: 11796480 weights + 65536 (T) + 4608 (rows) + 96 (meta) = 11866720.
// ---------------------------------------------------------------------------
__global__ __launch_bounds__(256) void k_cvt(
    const float* __restrict__ hs, const float* __restrict__ W1,
    const float* __restrict__ W2, const float* __restrict__ A1,
    const float* __restrict__ B1, const float* __restrict__ B2,
    const float* __restrict__ A2,
    u16* __restrict__ Xbf, u16* __restrict__ W1bf, u16* __restrict__ W2bf,
    u16* __restrict__ A1bf, u16* __restrict__ B1s, u16* __restrict__ B2s,
    u16* __restrict__ A2bf, float* __restrict__ T, int* __restrict__ rows,
    int* __restrict__ meta) {
  int i = blockIdx.x * 256 + threadIdx.x;
  if (i < 2097152) { Xbf[i] = f2bf(hs[i]); return; }
  i -= 2097152;
  if (i < 4194304) { W1bf[i] = f2bf(W1[i]); return; }
  i -= 4194304;
  if (i < 4194304) { W2bf[i] = f2bf(W2[i]); return; }
  i -= 4194304;
  if (i < 131072) { A1bf[i] = f2bf(A1[i]); return; }
  i -= 131072;
  if (i < 524288) { B1s[i] = f2bf(2.0f * B1[i]); return; }  // [E,H,R]
  i -= 524288;
  if (i < 131072) { B2s[i] = f2bf(2.0f * B2[i]); return; }  // [E,D,R]
  i -= 131072;
  if (i < 524288) { A2bf[i] = f2bf(A2[i]); return; }        // [E,R,H] plain
  i -= 524288;
  if (i < 65536) { T[i] = 0.f; return; }
  i -= 65536;
  if (i < 4608) { rows[i] = -1; return; }
  i -= 4608;
  if (i < 96) meta[i] = 0;
}

// ---------------------------------------------------------------------------
// Router: 1 wave per token; top-2 renormalized softmax = sigmoid(l0-l1).
// ---------------------------------------------------------------------------
__global__ __launch_bounds__(256) void k_router(
    const float* __restrict__ x, const float* __restrict__ gate,
    int* __restrict__ sel, float* __restrict__ wgt, int* __restrict__ cnt) {
  const int lane = threadIdx.x & 63;
  const int wv = threadIdx.x >> 6;
  const int t = blockIdx.x * 4 + wv;
  const float* xp = x + (size_t)t * 1024 + lane * 16;
  float4 xv[4];
#pragma unroll
  for (int i = 0; i < 4; ++i) xv[i] = *(const float4*)(xp + i * 4);
  float acc[8];
#pragma unroll
  for (int e = 0; e < 8; ++e) {
    const float* gp = gate + e * 1024 + lane * 16;
    float s = 0.f;
#pragma unroll
    for (int i = 0; i < 4; ++i) {
      float4 g = *(const float4*)(gp + i * 4);
      s += xv[i].x * g.x + xv[i].y * g.y + xv[i].z * g.z + xv[i].w * g.w;
    }
    acc[e] = s;
  }
#pragma unroll
  for (int e = 0; e < 8; ++e)
    for (int off = 32; off > 0; off >>= 1) acc[e] += __shfl_xor(acc[e], off);
  if (lane == 0) {
    int e0 = 0; float l0 = acc[0];
#pragma unroll
    for (int e = 1; e < 8; ++e) if (acc[e] > l0) { l0 = acc[e]; e0 = e; }
    int e1 = (e0 == 0) ? 1 : 0; float l1 = acc[e1];
#pragma unroll
    for (int e = 0; e < 8; ++e)
      if (e != e0 && acc[e] > l1) { l1 = acc[e]; e1 = e; }
    float p = 1.f / (1.f + __expf(l1 - l0));
    sel[2 * t] = e0; sel[2 * t + 1] = e1;
    wgt[2 * t] = p;  wgt[2 * t + 1] = 1.f - p;
    atomicAdd(&cnt[e0], 1);
    atomicAdd(&cnt[e1], 1);
  }
}

// ---------------------------------------------------------------------------
// Parallel scan: per-expert segment starts (padded to 64), tile->expert map.
// One block, 128 threads; every thread recomputes the 8-entry prefix.
// ---------------------------------------------------------------------------
__global__ void k_scan(const int* __restrict__ counts, int* __restrict__ cursors,
                       int* __restrict__ tile_expert) {
  int tid = threadIdx.x;
  int off[9];
  off[0] = 0;
#pragma unroll
  for (int e = 0; e < 8; ++e) off[e + 1] = off[e] + ((counts[e] + 63) & ~63);
  if (tid < 8) cursors[tid] = off[tid];
  if (tid < 72) {
    int pos = tid * 64;
    int e = 0;
    while (e < 7 && pos >= off[e + 1]) ++e;
    tile_expert[tid] = e;
  }
}

__global__ __launch_bounds__(256) void k_scatter(const int* __restrict__ sel,
                                                 int* __restrict__ cursors,
                                                 int* __restrict__ rows) {
  int t = blockIdx.x * 256 + threadIdx.x;
  if (t >= 2048) return;
  int e0 = sel[2 * t], e1 = sel[2 * t + 1];
  rows[atomicAdd(&cursors[e0], 1)] = 2 * t;
  rows[atomicAdd(&cursors[e1], 1)] = 2 * t + 1;
}

// ---------------------------------------------------------------------------
// bf16 GEMM, C[m,n] = sum_k A[m,k]*B[n,k] (+bias[n] on bf16 path).
// 128x128 tile, BK=64, 256 threads, 16x16x32 MFMA, global_load_lds w=16,
// XOR chunk swizzle. blockIdx.z = split-K slice.
// ---------------------------------------------------------------------------
__global__ __launch_bounds__(256, 2) void gemm_bt(
    const u16* __restrict__ A, const u16* __restrict__ B, void* __restrict__ Cv,
    int K, int ldc, int Ksub, size_t Cstride_elems, int outbf,
    const float* __restrict__ bias) {
  __shared__ alignas(16) u16 lsA[128 * 64];
  __shared__ alignas(16) u16 lsB[128 * 64];
  const int tid = threadIdx.x;
  const int lane = tid & 63;
  const int w = tid >> 6;
  const int m0 = blockIdx.x * 128;
  const int n0 = blockIdx.y * 128;
  const int z = blockIdx.z;
  const int wm = w & 1, wn = w >> 1;

  f32x4 acc[4][4] = {};

  const int sr = lane >> 3;
  const int sc = lane & 7;
  const int cg = sc ^ sr;
  const u16* Ag = A + (size_t)(m0 + w * 32 + sr) * K + (size_t)z * Ksub + cg * 8;
  const u16* Bg = B + (size_t)(n0 + w * 32 + sr) * K + (size_t)z * Ksub + cg * 8;
  u16* lA = lsA + w * 2048;
  u16* lB = lsB + w * 2048;

  const int fr = lane & 15;
  const int fq = lane >> 4;

  for (int kt = 0; kt < Ksub; kt += 64) {
#pragma unroll
    for (int j = 0; j < 4; ++j) {
      gload16(Ag + (size_t)j * 8 * K, lA + j * 512);
      gload16(Bg + (size_t)j * 8 * K, lB + j * 512);
    }
    Ag += 64; Bg += 64;
    __syncthreads();
#pragma unroll
    for (int s = 0; s < 2; ++s) {
      const int cl = (s * 4 + fq) ^ (fr & 7);
      bf16x8 av[4], bv[4];
#pragma unroll
      for (int i = 0; i < 4; ++i)
        av[i] = *(const bf16x8*)&lsA[(wm * 64 + i * 16 + fr) * 64 + cl * 8];
#pragma unroll
      for (int j = 0; j < 4; ++j)
        bv[j] = *(const bf16x8*)&lsB[(wn * 64 + j * 16 + fr) * 64 + cl * 8];
#pragma unroll
      for (int i = 0; i < 4; ++i)
#pragma unroll
        for (int j = 0; j < 4; ++j)
          acc[i][j] = __builtin_amdgcn_mfma_f32_16x16x32_bf16(av[i], bv[j], acc[i][j], 0, 0, 0);
    }
    __syncthreads();
  }

  const size_t zoff = (size_t)z * Cstride_elems;
  if (outbf) {
    u16* Co = (u16*)Cv + zoff;
#pragma unroll
    for (int i = 0; i < 4; ++i)
#pragma unroll
      for (int j = 0; j < 4; ++j)
#pragma unroll
        for (int r = 0; r < 4; ++r) {
          int m = m0 + wm * 64 + i * 16 + fq * 4 + r;
          int n = n0 + wn * 64 + j * 16 + fr;
          float bv2 = bias ? bias[n] : 0.f;
          Co[(size_t)m * ldc + n] = f2bf(acc[i][j][r] + bv2);
        }
  } else {
    float* Co = (float*)Cv + zoff;
#pragma unroll
    for (int i = 0; i < 4; ++i)
#pragma unroll
      for (int j = 0; j < 4; ++j)
#pragma unroll
        for (int r = 0; r < 4; ++r) {
          int m = m0 + wm * 64 + i * 16 + fq * 4 + r;
          int n = n0 + wn * 64 + j * 16 + fr;
          Co[(size_t)m * ldc + n] = acc[i][j][r];
        }
  }
}

// ---------------------------------------------------------------------------
// Expert-sorted LoRA1 + silu: block = (sorted tile of 64 rows) x (256 h).
// Row metadata (p, w, LX row) staged to LDS once -> main loop has no
// dependent global scalar chains. B1[e][h][:] in 16 registers, reused 64x.
// Zw[p,h] = w_p * silu(C1[t,h] + LX[t,e]·B1s[e][h]).
// ---------------------------------------------------------------------------
__global__ __launch_bounds__(256) void k_lora1(
    const u16* __restrict__ C1, const float* __restrict__ LX,
    const u16* __restrict__ B1s, const int* __restrict__ rows,
    const int* __restrict__ tile_expert, const float* __restrict__ wgt,
    u16* __restrict__ Zw) {
  const int tile = blockIdx.x;
  const int tid = threadIdx.x;
  const int h = blockIdx.y * 256 + tid;
  const int e = tile_expert[tile];
  __shared__ int sp[64];
  __shared__ float sw[64];
  __shared__ alignas(16) float slx[64][16];
  if (tid < 64) {
    int p = rows[tile * 64 + tid];
    sp[tid] = p;
    sw[tid] = (p >= 0) ? wgt[p] : 0.f;
  }
  __syncthreads();
  {
    int i0 = tid >> 4, r = tid & 15;
#pragma unroll
    for (int rep = 0; rep < 4; ++rep) {
      int i = i0 + rep * 16;
      int p = sp[i];
      slx[i][r] = (p >= 0) ? LX[(p >> 1) * 128 + e * 16 + r] : 0.f;
    }
  }
  float bw[16];
  load16bf(B1s + (size_t)e * 65536 + (size_t)h * 16, bw);
  __syncthreads();
#pragma unroll 4
  for (int i = 0; i < 64; ++i) {
    int p = sp[i];
    if (p < 0) continue;  // block-uniform
    int t = p >> 1;
    float c = bf2f(C1[(size_t)t * 4096 + h]);
    float d = 0.f;
#pragma unroll
    for (int rr = 0; rr < 4; ++rr) {
      float4 v = *(const float4*)&slx[i][rr * 4];  // LDS broadcast
      d += v.x * bw[rr * 4] + v.y * bw[rr * 4 + 1] +
           v.z * bw[rr * 4 + 2] + v.w * bw[rr * 4 + 3];
    }
    float z = c + d;
    float s = z / (1.f + __expf(-z));
    Zw[(size_t)p * 4096 + h] = f2bf(sw[i] * s);
  }
}

// ---------------------------------------------------------------------------
// am[t,h] = Zw[2t,h] + Zw[2t+1,h]  (bf16, vectorized x8)
// ---------------------------------------------------------------------------
__global__ __launch_bounds__(256) void k_am(const u16* __restrict__ Zw,
                                            u16* __restrict__ am) {
  int gid = blockIdx.x * 256 + threadIdx.x;
  int t = gid >> 9;
  int hh = (gid & 511) * 8;
  const u16* z0 = Zw + (size_t)(2 * t) * 4096 + hh;
  const u16* z1 = Zw + (size_t)(2 * t + 1) * 4096 + hh;
  uint4 a = *(const uint4*)z0;
  uint4 b = *(const uint4*)z1;
  u32 va[4] = {a.x, a.y, a.z, a.w};
  u32 vb[4] = {b.x, b.y, b.z, b.w};
  u32 out[4];
#pragma unroll
  for (int i = 0; i < 4; ++i) {
    float lo = __uint_as_float(va[i] << 16) + __uint_as_float(vb[i] << 16);
    float hi = __uint_as_float(va[i] & 0xFFFF0000u) + __uint_as_float(vb[i] & 0xFFFF0000u);
    out[i] = (u32)f2bf(lo) | ((u32)f2bf(hi) << 16);
  }
  *(uint4*)(am + (size_t)t * 4096 + hh) = *(uint4*)out;
}

// ---------------------------------------------------------------------------
// T[p,r] = sum_h Zw[p,h] * A2bf[e][r][h] via MFMA. Grid (72 tiles, 4 k-splits),
// 4 waves = 4 m-subtiles of 16 sorted rows. A-frag: Zw[p(fr)][k], B-frag:
// A2bf[e][fr][k] (both contiguous 16B loads, no LDS). D: m=fq*4+reg, n=fr.
// atomicAdd into zeroed T.
// ---------------------------------------------------------------------------
__global__ __launch_bounds__(256) void k_tg2(
    const u16* __restrict__ Zw, const u16* __restrict__ A2bf,
    const int* __restrict__ rows, const int* __restrict__ tile_expert,
    float* __restrict__ T) {
  const int tile = blockIdx.x;
  const int k0 = blockIdx.y * 1024;
  const int tid = threadIdx.x;
  const int lane = tid & 63, wv = tid >> 6;
  const int fr = lane & 15, fq = lane >> 4;
  const int e = tile_expert[tile];
  int p = rows[tile * 64 + wv * 16 + fr];
  int p0 = p < 0 ? 0 : p;
  const u16* zp = Zw + (size_t)p0 * 4096 + k0 + fq * 8;
  const u16* ap = A2bf + (size_t)e * 65536 + (size_t)fr * 4096 + k0 + fq * 8;
  f32x4 acc = {};
#pragma unroll 8
  for (int k = 0; k < 1024; k += 32) {
    bf16x8 av = *(const bf16x8*)(zp + k);
    bf16x8 bv = *(const bf16x8*)(ap + k);
    acc = __builtin_amdgcn_mfma_f32_16x16x32_bf16(av, bv, acc, 0, 0, 0);
  }
#pragma unroll
  for (int r = 0; r < 4; ++r) {
    int pm = rows[tile * 64 + wv * 16 + fq * 4 + r];
    if (pm >= 0) atomicAdd(&T[pm * 16 + fr], acc[r]);
  }
}

// ---------------------------------------------------------------------------
// out = sum_z F2p[z] + b2 + T[2t]·B2s[e0][d] + T[2t+1]·B2s[e1][d]
// ---------------------------------------------------------------------------
__global__ __launch_bounds__(256) void k_final(
    const float* __restrict__ F2p, const float* __restrict__ b2,
    const u16* __restrict__ B2s, const float* __restrict__ T,
    const int* __restrict__ sel, float* __restrict__ out) {
  const int idx = blockIdx.x * 256 + threadIdx.x;
  const int t = idx >> 10, d = idx & 1023;
  const int e0 = sel[2 * t], e1 = sel[2 * t + 1];
  float s = F2p[idx] + F2p[idx + 2097152] + F2p[idx + 4194304] +
            F2p[idx + 6291456] + b2[d];
  float f0[16], f1[16];
  load16bf(B2s + (size_t)e0 * 16384 + d * 16, f0);
  load16bf(B2s + (size_t)e1 * 16384 + d * 16, f1);
  const float* tp0 = T + (2 * t) * 16;
  const float* tp1 = T + (2 * t + 1) * 16;
#pragma unroll
  for (int r = 0; r < 16; ++r) s += tp0[r] * f0[r] + tp1[r] * f1[r];
  out[idx] = s;
}

// ---------------------------------------------------------------------------
extern "C" void kernel_launch(void* const* d_in, const int* in_sizes, int n_in,
                              void* d_out, int out_size, void* d_ws, size_t ws_size,
                              hipStream_t stream) {
  const float* hs   = (const float*)d_in[0];
  const float* gate = (const float*)d_in[1];
  const float* W1   = (const float*)d_in[2];
  const float* b1   = (const float*)d_in[3];
  const float* W2   = (const float*)d_in[4];
  const float* b2   = (const float*)d_in[5];
  const float* A1   = (const float*)d_in[6];
  const float* B1   = (const float*)d_in[7];
  const float* A2   = (const float*)d_in[8];
  const float* B2   = (const float*)d_in[9];

  char* ws = (char*)d_ws;
  size_t off = 0;
  auto alloc = [&](size_t bytes) -> void* {
    void* p = ws + off;
    off += (bytes + 255) & ~(size_t)255;
    return p;
  };
  u16*   Xbf  = (u16*)alloc(2097152ull * 2);        // x bf16 [2048,1024]
  u16*   W1bf = (u16*)alloc(4194304ull * 2);        // [4096,1024]
  u16*   W2bf = (u16*)alloc(4194304ull * 2);        // [1024,4096]
  u16*   A1bf = (u16*)alloc(131072ull * 2);         // [128,1024]
  u16*   B1s  = (u16*)alloc(524288ull * 2);         // 2*B1 [E,4096,16]
  u16*   B2s  = (u16*)alloc(131072ull * 2);         // 2*B2 [E,1024,16]
  u16*   A2bf = (u16*)alloc(524288ull * 2);         // A2 [E,16,4096] bf16
  u16*   C1   = (u16*)alloc(2048ull * 4096 * 2);    // x@W1^T + b1, bf16
  float* LX   = (float*)alloc(2048ull * 128 * 4);   // x@A1_all^T fp32
  u16*   am   = (u16*)alloc(2048ull * 4096 * 2);    // Zw[2t]+Zw[2t+1]
  u16*   Zw   = (u16*)alloc(4096ull * 4096 * 2);    // w_p*silu per pair (32MB)
  float* F2p  = (float*)Zw;                         // ALIAS: Zw dead before gemm2
  float* T    = (float*)alloc(4096ull * 16 * 4);    // a@A2^T (w folded later? no: raw)
  int*   sel  = (int*)alloc(2048ull * 2 * 4);
  float* wgt  = (float*)alloc(2048ull * 2 * 4);
  int*   meta = (int*)alloc(96 * 4);                // counts8|cursors8|tilee72
  int*   rows = (int*)alloc(4608 * 4);
  int* counts = meta;
  int* cursors = meta + 8;
  int* tile_expert = meta + 16;

  k_cvt<<<46356, 256, 0, stream>>>(hs, W1, W2, A1, B1, B2, A2,
                                   Xbf, W1bf, W2bf, A1bf, B1s, B2s, A2bf,
                                   T, rows, meta);
  k_router<<<512, 256, 0, stream>>>(hs, gate, sel, wgt, counts);
  k_scan<<<1, 128, 0, stream>>>(counts, cursors, tile_expert);
  k_scatter<<<8, 256, 0, stream>>>(sel, cursors, rows);
  // C1 = X @ W1^T + b1 (bf16), M=2048 N=4096 K=1024
  gemm_bt<<<dim3(16, 32, 1), 256, 0, stream>>>(Xbf, W1bf, (void*)C1, 1024, 4096, 1024, 0, 1, b1);
  // LX = X @ A1_all^T (fp32), N=128
  gemm_bt<<<dim3(16, 1, 1), 256, 0, stream>>>(Xbf, A1bf, (void*)LX, 1024, 128, 1024, 0, 0, nullptr);
  k_lora1<<<dim3(72, 16), 256, 0, stream>>>(C1, LX, B1s, rows, tile_expert, wgt, Zw);
  k_am<<<4096, 256, 0, stream>>>(Zw, am);
  // T[p,:] = Zw[p,:] @ A2[e_p]^T  (MFMA, rank-16)
  k_tg2<<<dim3(72, 4), 256, 0, stream>>>(Zw, A2bf, rows, tile_expert, T);
  // F2p[z] = am @ W2^T (split-K=4), M=2048 N=1024 K=4096
  gemm_bt<<<dim3(16, 8, 4), 256, 0, stream>>>(am, W2bf, (void*)F2p, 4096, 1024, 1024, 2097152, 0, nullptr);
  k_final<<<8192, 256, 0, stream>>>(F2p, b2, B2s, T, sel, (float*)d_out);
}

// Round 4
// 258.351 us; speedup vs baseline: 1.5809x; 1.2917x over previous
//
#include <hip/hip_runtime.h>
#include <hip/hip_bf16.h>
#include <stdint.h>

typedef unsigned short u16;
typedef unsigned int u32;

using bf16x8 = __attribute__((ext_vector_type(8))) __bf16;  // 4 VGPRs: MFMA A/B operand
using f32x4  = __attribute__((ext_vector_type(4))) float;   // MFMA C/D operand

#define AS1 __attribute__((address_space(1)))
#define AS3 __attribute__((address_space(3)))

// fp32 -> bf16 round-to-nearest-even
__device__ __forceinline__ u16 f2bf(float x) {
  u32 u = __float_as_uint(x);
  u = (u + 0x7FFFu + ((u >> 16) & 1u)) >> 16;
  return (u16)u;
}
__device__ __forceinline__ float bf2f(u32 bits) { return __uint_as_float(bits << 16); }

// async global->LDS, 16B per lane. LDS dest = wave-uniform base + lane*16.
__device__ __forceinline__ void gload16(const void* g, void* l) {
  __builtin_amdgcn_global_load_lds((AS1 void*)(const_cast<void*>(g)),
                                   (AS3 void*)l, 16, 0, 0);
}

// load 16 contiguous bf16 (32B, aligned) into 16 floats
__device__ __forceinline__ void load16bf(const u16* p, float* f) {
  uint4 a = *(const uint4*)(p);
  uint4 b = *(const uint4*)(p + 8);
  u32 v[8] = {a.x, a.y, a.z, a.w, b.x, b.y, b.z, b.w};
#pragma unroll
  for (int i = 0; i < 8; ++i) {
    f[2 * i]     = __uint_as_float(v[i] << 16);
    f[2 * i + 1] = __uint_as_float(v[i] & 0xFFFF0000u);
  }
}

// ---------------------------------------------------------------------------
// Convert / repack all weights to bf16 (LORA_SCALE=2.0 folded into B1,B2).
// A2 kept in original [E,16,4096] layout (MFMA B-operand for k_tg2).
// Total: 11,796,480 elements = 46080 * 256.
// ---------------------------------------------------------------------------
__global__ __launch_bounds__(256) void k_cvt(
    const float* __restrict__ hs, const float* __restrict__ W1,
    const float* __restrict__ W2, const float* __restrict__ A1,
    const float* __restrict__ B1, const float* __restrict__ B2,
    const float* __restrict__ A2,
    u16* __restrict__ Xbf, u16* __restrict__ W1bf, u16* __restrict__ W2bf,
    u16* __restrict__ A1bf, u16* __restrict__ B1s, u16* __restrict__ B2s,
    u16* __restrict__ A2bf) {
  int i = blockIdx.x * 256 + threadIdx.x;
  if (i < 2097152) { Xbf[i] = f2bf(hs[i]); return; }
  i -= 2097152;
  if (i < 4194304) { W1bf[i] = f2bf(W1[i]); return; }
  i -= 4194304;
  if (i < 4194304) { W2bf[i] = f2bf(W2[i]); return; }
  i -= 4194304;
  if (i < 131072) { A1bf[i] = f2bf(A1[i]); return; }
  i -= 131072;
  if (i < 524288) { B1s[i] = f2bf(2.0f * B1[i]); return; }  // [E,H,R]
  i -= 524288;
  if (i < 131072) { B2s[i] = f2bf(2.0f * B2[i]); return; }  // [E,D,R]
  i -= 131072;
  A2bf[i] = f2bf(A2[i]);                                    // [E,R,H] plain
}

// ---------------------------------------------------------------------------
// Router: 1 wave per token; top-2 renormalized softmax = sigmoid(l0-l1).
// NO atomics (R3 post-mortem: 4096 same-line atomicAdds cost ~50 us).
// ---------------------------------------------------------------------------
__global__ __launch_bounds__(256) void k_router(
    const float* __restrict__ x, const float* __restrict__ gate,
    int* __restrict__ sel, float* __restrict__ wgt) {
  const int lane = threadIdx.x & 63;
  const int wv = threadIdx.x >> 6;
  const int t = blockIdx.x * 4 + wv;
  const float* xp = x + (size_t)t * 1024 + lane * 16;
  float4 xv[4];
#pragma unroll
  for (int i = 0; i < 4; ++i) xv[i] = *(const float4*)(xp + i * 4);
  float acc[8];
#pragma unroll
  for (int e = 0; e < 8; ++e) {
    const float* gp = gate + e * 1024 + lane * 16;
    float s = 0.f;
#pragma unroll
    for (int i = 0; i < 4; ++i) {
      float4 g = *(const float4*)(gp + i * 4);
      s += xv[i].x * g.x + xv[i].y * g.y + xv[i].z * g.z + xv[i].w * g.w;
    }
    acc[e] = s;
  }
#pragma unroll
  for (int e = 0; e < 8; ++e)
    for (int off = 32; off > 0; off >>= 1) acc[e] += __shfl_xor(acc[e], off);
  if (lane == 0) {
    int e0 = 0; float l0 = acc[0];
#pragma unroll
    for (int e = 1; e < 8; ++e) if (acc[e] > l0) { l0 = acc[e]; e0 = e; }
    int e1 = (e0 == 0) ? 1 : 0; float l1 = acc[e1];
#pragma unroll
    for (int e = 0; e < 8; ++e)
      if (e != e0 && acc[e] > l1) { l1 = acc[e]; e1 = e; }
    float p = 1.f / (1.f + __expf(l1 - l0));
    sel[2 * t] = e0; sel[2 * t + 1] = e1;
    wgt[2 * t] = p;  wgt[2 * t + 1] = 1.f - p;
  }
}

// ---------------------------------------------------------------------------
// Deterministic 8-bin sort of 4096 (token,slot) pairs by expert. One block,
// 1024 threads = 16 waves. Ballot-based within-wave ranks, LDS cross-wave
// prefix, segments padded to 64. Zero global atomics.
// ---------------------------------------------------------------------------
__global__ __launch_bounds__(1024) void k_sort(const int* __restrict__ sel,
                                               int* __restrict__ rows,
                                               int* __restrict__ tile_expert) {
  __shared__ int wavehist[16][8];
  __shared__ int stot[8];
  __shared__ int waveoff[16][8];
  const int tid = threadIdx.x;
  const int lane = tid & 63, w = tid >> 6;
  for (int i = tid; i < 4608; i += 1024) rows[i] = -1;
  int ev[4], rk[4];
  int wc[8] = {};
  const unsigned long long ltmask = (1ull << lane) - 1;
#pragma unroll
  for (int j = 0; j < 4; ++j) {
    int p = w * 256 + j * 64 + lane;
    ev[j] = sel[p];
#pragma unroll
    for (int ex = 0; ex < 8; ++ex) {
      unsigned long long m = __ballot(ev[j] == ex);
      if (ev[j] == ex) rk[j] = wc[ex] + __popcll(m & ltmask);
      wc[ex] += __popcll(m);
    }
  }
#pragma unroll
  for (int ex = 0; ex < 8; ++ex)
    if (lane == ex) wavehist[w][ex] = wc[ex];  // wc uniform across wave
  __syncthreads();
  if (tid < 8) {
    int s = 0;
    for (int ww = 0; ww < 16; ++ww) s += wavehist[ww][tid];
    stot[tid] = s;
  }
  __syncthreads();
  if (tid < 128) {
    int ww = tid >> 3, ex = tid & 7;
    int base = 0;
    for (int e2 = 0; e2 < ex; ++e2) base += (stot[e2] + 63) & ~63;
    for (int w2 = 0; w2 < ww; ++w2) base += wavehist[w2][ex];
    waveoff[ww][ex] = base;
  } else if (tid < 200) {
    int tt = tid - 128;
    int pos = tt * 64, acc2 = 0, e2 = 0;
    while (e2 < 7) {
      int na = acc2 + ((stot[e2] + 63) & ~63);
      if (pos < na) break;
      acc2 = na; ++e2;
    }
    tile_expert[tt] = e2;
  }
  __syncthreads();
#pragma unroll
  for (int j = 0; j < 4; ++j)
    rows[waveoff[w][ev[j]] + rk[j]] = w * 256 + j * 64 + lane;
}

// ---------------------------------------------------------------------------
// bf16 GEMM, C[m,n] = sum_k A[m,k]*B[n,k] (+bias[n] for n<bias_n on bf16 path).
// 128x128 tile, BK=64, 256 threads, 16x16x32 MFMA, global_load_lds w=16,
// XOR chunk swizzle. blockIdx.z = split-K slice.
// ---------------------------------------------------------------------------
__global__ __launch_bounds__(256, 2) void gemm_bt(
    const u16* __restrict__ A, const u16* __restrict__ B, void* __restrict__ Cv,
    int K, int ldc, int Ksub, size_t Cstride_elems, int outbf,
    const float* __restrict__ bias, int bias_n) {
  __shared__ alignas(16) u16 lsA[128 * 64];
  __shared__ alignas(16) u16 lsB[128 * 64];
  const int tid = threadIdx.x;
  const int lane = tid & 63;
  const int w = tid >> 6;
  const int m0 = blockIdx.x * 128;
  const int n0 = blockIdx.y * 128;
  const int z = blockIdx.z;
  const int wm = w & 1, wn = w >> 1;

  f32x4 acc[4][4] = {};

  const int sr = lane >> 3;
  const int sc = lane & 7;
  const int cg = sc ^ sr;
  const u16* Ag = A + (size_t)(m0 + w * 32 + sr) * K + (size_t)z * Ksub + cg * 8;
  const u16* Bg = B + (size_t)(n0 + w * 32 + sr) * K + (size_t)z * Ksub + cg * 8;
  u16* lA = lsA + w * 2048;
  u16* lB = lsB + w * 2048;

  const int fr = lane & 15;
  const int fq = lane >> 4;

  for (int kt = 0; kt < Ksub; kt += 64) {
#pragma unroll
    for (int j = 0; j < 4; ++j) {
      gload16(Ag + (size_t)j * 8 * K, lA + j * 512);
      gload16(Bg + (size_t)j * 8 * K, lB + j * 512);
    }
    Ag += 64; Bg += 64;
    __syncthreads();
#pragma unroll
    for (int s = 0; s < 2; ++s) {
      const int cl = (s * 4 + fq) ^ (fr & 7);
      bf16x8 av[4], bv[4];
#pragma unroll
      for (int i = 0; i < 4; ++i)
        av[i] = *(const bf16x8*)&lsA[(wm * 64 + i * 16 + fr) * 64 + cl * 8];
#pragma unroll
      for (int j = 0; j < 4; ++j)
        bv[j] = *(const bf16x8*)&lsB[(wn * 64 + j * 16 + fr) * 64 + cl * 8];
#pragma unroll
      for (int i = 0; i < 4; ++i)
#pragma unroll
        for (int j = 0; j < 4; ++j)
          acc[i][j] = __builtin_amdgcn_mfma_f32_16x16x32_bf16(av[i], bv[j], acc[i][j], 0, 0, 0);
    }
    __syncthreads();
  }

  const size_t zoff = (size_t)z * Cstride_elems;
  if (outbf) {
    u16* Co = (u16*)Cv + zoff;
#pragma unroll
    for (int i = 0; i < 4; ++i)
#pragma unroll
      for (int j = 0; j < 4; ++j)
#pragma unroll
        for (int r = 0; r < 4; ++r) {
          int m = m0 + wm * 64 + i * 16 + fq * 4 + r;
          int n = n0 + wn * 64 + j * 16 + fr;
          float bv2 = (bias && n < bias_n) ? bias[n] : 0.f;
          Co[(size_t)m * ldc + n] = f2bf(acc[i][j][r] + bv2);
        }
  } else {
    float* Co = (float*)Cv + zoff;
#pragma unroll
    for (int i = 0; i < 4; ++i)
#pragma unroll
      for (int j = 0; j < 4; ++j)
#pragma unroll
        for (int r = 0; r < 4; ++r) {
          int m = m0 + wm * 64 + i * 16 + fq * 4 + r;
          int n = n0 + wn * 64 + j * 16 + fr;
          Co[(size_t)m * ldc + n] = acc[i][j][r];
        }
  }
}

// ---------------------------------------------------------------------------
// Expert-sorted LoRA1 + silu. C1cat is [2048, 4224]: cols 0..4095 = x@W1^T+b1,
// cols 4096..4223 = x@A1_all^T (bf16). Block = (tile of 64 rows) x (256 h).
// Zw[p,h] = w_p * silu(C1[t,h] + LX[t,e]·B1s[e][h]).
// ---------------------------------------------------------------------------
__global__ __launch_bounds__(256) void k_lora1(
    const u16* __restrict__ C1, const u16* __restrict__ B1s,
    const int* __restrict__ rows, const int* __restrict__ tile_expert,
    const float* __restrict__ wgt, u16* __restrict__ Zw) {
  const int tile = blockIdx.x;
  const int tid = threadIdx.x;
  const int h = blockIdx.y * 256 + tid;
  const int e = tile_expert[tile];
  __shared__ int sp[64];
  __shared__ float sw[64];
  __shared__ alignas(16) float slx[64][16];
  if (tid < 64) {
    int p = rows[tile * 64 + tid];
    sp[tid] = p;
    sw[tid] = (p >= 0) ? wgt[p] : 0.f;
  }
  __syncthreads();
  {
    int i0 = tid >> 4, r = tid & 15;
#pragma unroll
    for (int rep = 0; rep < 4; ++rep) {
      int i = i0 + rep * 16;
      int p = sp[i];
      slx[i][r] = (p >= 0) ? bf2f(C1[(size_t)(p >> 1) * 4224 + 4096 + e * 16 + r]) : 0.f;
    }
  }
  float bw[16];
  load16bf(B1s + (size_t)e * 65536 + (size_t)h * 16, bw);
  __syncthreads();
#pragma unroll 4
  for (int i = 0; i < 64; ++i) {
    int p = sp[i];
    if (p < 0) continue;  // block-uniform
    int t = p >> 1;
    float c = bf2f(C1[(size_t)t * 4224 + h]);
    float d = 0.f;
#pragma unroll
    for (int rr = 0; rr < 4; ++rr) {
      float4 v = *(const float4*)&slx[i][rr * 4];  // LDS broadcast
      d += v.x * bw[rr * 4] + v.y * bw[rr * 4 + 1] +
           v.z * bw[rr * 4 + 2] + v.w * bw[rr * 4 + 3];
    }
    float z = c + d;
    float s = z / (1.f + __expf(-z));
    Zw[(size_t)p * 4096 + h] = f2bf(sw[i] * s);
  }
}

// ---------------------------------------------------------------------------
// am[t,h] = Zw[2t,h] + Zw[2t+1,h]  (bf16, vectorized x8)
// ---------------------------------------------------------------------------
__global__ __launch_bounds__(256) void k_am(const u16* __restrict__ Zw,
                                            u16* __restrict__ am) {
  int gid = blockIdx.x * 256 + threadIdx.x;
  int t = gid >> 9;
  int hh = (gid & 511) * 8;
  const u16* z0 = Zw + (size_t)(2 * t) * 4096 + hh;
  const u16* z1 = Zw + (size_t)(2 * t + 1) * 4096 + hh;
  uint4 a = *(const uint4*)z0;
  uint4 b = *(const uint4*)z1;
  u32 va[4] = {a.x, a.y, a.z, a.w};
  u32 vb[4] = {b.x, b.y, b.z, b.w};
  u32 out[4];
#pragma unroll
  for (int i = 0; i < 4; ++i) {
    float lo = __uint_as_float(va[i] << 16) + __uint_as_float(vb[i] << 16);
    float hi = __uint_as_float(va[i] & 0xFFFF0000u) + __uint_as_float(vb[i] & 0xFFFF0000u);
    out[i] = (u32)f2bf(lo) | ((u32)f2bf(hi) << 16);
  }
  *(uint4*)(am + (size_t)t * 4096 + hh) = *(uint4*)out;
}

// ---------------------------------------------------------------------------
// Tp[z][p][r] = sum_{k in split z} Zw[p,k] * A2bf[e][r][k] via MFMA.
// Grid (72 tiles, 4 k-splits), 4 waves = 4 m-subtiles of 16 sorted rows.
// Plain stores (no atomics); k_tred sums the 4 partials.
// ---------------------------------------------------------------------------
__global__ __launch_bounds__(256) void k_tg2(
    const u16* __restrict__ Zw, const u16* __restrict__ A2bf,
    const int* __restrict__ rows, const int* __restrict__ tile_expert,
    float* __restrict__ Tp) {
  const int tile = blockIdx.x;
  const int z = blockIdx.y;
  const int k0 = z * 1024;
  const int tid = threadIdx.x;
  const int lane = tid & 63, wv = tid >> 6;
  const int fr = lane & 15, fq = lane >> 4;
  const int e = tile_expert[tile];
  int p = rows[tile * 64 + wv * 16 + fr];
  int p0 = p < 0 ? 0 : p;
  const u16* zp = Zw + (size_t)p0 * 4096 + k0 + fq * 8;
  const u16* ap = A2bf + (size_t)e * 65536 + (size_t)fr * 4096 + k0 + fq * 8;
  f32x4 acc = {};
#pragma unroll 8
  for (int k = 0; k < 1024; k += 32) {
    bf16x8 av = *(const bf16x8*)(zp + k);
    bf16x8 bv = *(const bf16x8*)(ap + k);
    acc = __builtin_amdgcn_mfma_f32_16x16x32_bf16(av, bv, acc, 0, 0, 0);
  }
#pragma unroll
  for (int r = 0; r < 4; ++r) {
    int pm = rows[tile * 64 + wv * 16 + fq * 4 + r];
    if (pm >= 0) Tp[(size_t)z * 65536 + pm * 16 + fr] = acc[r];
  }
}

__global__ __launch_bounds__(256) void k_tred(const float* __restrict__ Tp,
                                              float* __restrict__ T) {
  int i = blockIdx.x * 256 + threadIdx.x;
  T[i] = Tp[i] + Tp[i + 65536] + Tp[i + 131072] + Tp[i + 196608];
}

// ---------------------------------------------------------------------------
// out = sum_z F2p[z] + b2 + T[2t]·B2s[e0][d] + T[2t+1]·B2s[e1][d]
// ---------------------------------------------------------------------------
__global__ __launch_bounds__(256) void k_final(
    const float* __restrict__ F2p, const float* __restrict__ b2,
    const u16* __restrict__ B2s, const float* __restrict__ T,
    const int* __restrict__ sel, float* __restrict__ out) {
  const int idx = blockIdx.x * 256 + threadIdx.x;
  const int t = idx >> 10, d = idx & 1023;
  const int e0 = sel[2 * t], e1 = sel[2 * t + 1];
  float s = F2p[idx] + F2p[idx + 2097152] + F2p[idx + 4194304] +
            F2p[idx + 6291456] + b2[d];
  float f0[16], f1[16];
  load16bf(B2s + (size_t)e0 * 16384 + d * 16, f0);
  load16bf(B2s + (size_t)e1 * 16384 + d * 16, f1);
  const float* tp0 = T + (2 * t) * 16;
  const float* tp1 = T + (2 * t + 1) * 16;
#pragma unroll
  for (int r = 0; r < 16; ++r) s += tp0[r] * f0[r] + tp1[r] * f1[r];
  out[idx] = s;
}

// ---------------------------------------------------------------------------
extern "C" void kernel_launch(void* const* d_in, const int* in_sizes, int n_in,
                              void* d_out, int out_size, void* d_ws, size_t ws_size,
                              hipStream_t stream) {
  const float* hs   = (const float*)d_in[0];
  const float* gate = (const float*)d_in[1];
  const float* W1   = (const float*)d_in[2];
  const float* b1   = (const float*)d_in[3];
  const float* W2   = (const float*)d_in[4];
  const float* b2   = (const float*)d_in[5];
  const float* A1   = (const float*)d_in[6];
  const float* B1   = (const float*)d_in[7];
  const float* A2   = (const float*)d_in[8];
  const float* B2   = (const float*)d_in[9];

  char* ws = (char*)d_ws;
  size_t off = 0;
  auto alloc = [&](size_t bytes) -> void* {
    void* p = ws + off;
    off += (bytes + 255) & ~(size_t)255;
    return p;
  };
  u16*   Xbf  = (u16*)alloc(2097152ull * 2);        // x bf16 [2048,1024]
  u16*   W1bf = (u16*)alloc(4194304ull * 2);        // [4096,1024]
  u16*   A1bf = (u16*)alloc(131072ull * 2);         // [128,1024] CONTIGUOUS after W1bf
  u16*   W2bf = (u16*)alloc(4194304ull * 2);        // [1024,4096]
  u16*   B1s  = (u16*)alloc(524288ull * 2);         // 2*B1 [E,4096,16]
  u16*   B2s  = (u16*)alloc(131072ull * 2);         // 2*B2 [E,1024,16]
  u16*   A2bf = (u16*)alloc(524288ull * 2);         // A2 [E,16,4096] bf16
  u16*   C1   = (u16*)alloc(2048ull * 4224 * 2);    // [x@W1^T+b1 | x@A1^T] bf16
  u16*   am   = (u16*)alloc(2048ull * 4096 * 2);    // Zw[2t]+Zw[2t+1]
  u16*   Zw   = (u16*)alloc(4096ull * 4096 * 2);    // w_p*silu per pair (32MB)
  float* F2p  = (float*)Zw;                         // ALIAS: Zw dead before gemm2
  float* Tp   = (float*)alloc(4ull * 65536 * 4);    // per-k-split partials
  float* T    = (float*)alloc(65536ull * 4);
  int*   sel  = (int*)alloc(2048ull * 2 * 4);
  float* wgt  = (float*)alloc(2048ull * 2 * 4);
  int*   rows = (int*)alloc(4608 * 4);
  int*   tile_expert = (int*)alloc(72 * 4);

  k_cvt<<<46080, 256, 0, stream>>>(hs, W1, W2, A1, B1, B2, A2,
                                   Xbf, W1bf, W2bf, A1bf, B1s, B2s, A2bf);
  k_router<<<512, 256, 0, stream>>>(hs, gate, sel, wgt);
  k_sort<<<1, 1024, 0, stream>>>(sel, rows, tile_expert);
  // C1cat = X @ [W1|A1_all]^T (+b1 on first 4096 cols), M=2048 N=4224 K=1024
  gemm_bt<<<dim3(16, 33, 1), 256, 0, stream>>>(Xbf, W1bf, (void*)C1, 1024, 4224, 1024, 0, 1, b1, 4096);
  k_lora1<<<dim3(72, 16), 256, 0, stream>>>(C1, B1s, rows, tile_expert, wgt, Zw);
  k_am<<<4096, 256, 0, stream>>>(Zw, am);
  // Tp[z][p,:] = Zw[p, split z] @ A2[e_p]^T  (MFMA, rank-16)
  k_tg2<<<dim3(72, 4), 256, 0, stream>>>(Zw, A2bf, rows, tile_expert, Tp);
  k_tred<<<256, 256, 0, stream>>>(Tp, T);
  // F2p[z] = am @ W2^T (split-K=4), M=2048 N=1024 K=4096
  gemm_bt<<<dim3(16, 8, 4), 256, 0, stream>>>(am, W2bf, (void*)F2p, 4096, 1024, 1024, 2097152, 0, nullptr, 0);
  k_final<<<8192, 256, 0, stream>>>(F2p, b2, B2s, T, sel, (float*)d_out);
}